// Round 22
// baseline (228.874 us; speedup 1.0000x reference)
//
#include <hip/hip_runtime.h>
#include <hip/hip_bf16.h>
#include <stdint.h>

#define NN 8192
#define IN_DIM 343
#define IN_PAD 352
#define HID 1000
#define HID_PAD 1024
#define EPS 1e-5f
#define KH 4096           // split-K half length
#define BK2 64            // GEMM2 K-step
#define NT2 (KH / BK2)    // 64 K-tiles per block

typedef __attribute__((ext_vector_type(8))) short bf16x8;
typedef __attribute__((ext_vector_type(4))) float f32x4;
typedef __attribute__((ext_vector_type(16))) float f32x16;

static __device__ __forceinline__ unsigned short f2bf(float f) {
    union { float f; unsigned int u; } v; v.f = f;
    unsigned int u = v.u;
    unsigned int r = (u + 0x7FFFu + ((u >> 16) & 1u)) >> 16;   // RNE
    return (unsigned short)r;
}

static __device__ __forceinline__ unsigned cvt_pk_bf16(float lo, float hi) {
    unsigned r;
    asm("v_cvt_pk_bf16_f32 %0, %1, %2" : "=v"(r) : "v"(lo), "v"(hi));
    return r;
}

// ---------------- conversion kernels ----------------

__global__ __launch_bounds__(256) void k_cvt_feat(const float* __restrict__ src,
                                                  unsigned short* __restrict__ dst) {
    int idx = blockIdx.x * blockDim.x + threadIdx.x;
    if (idx >= NN * IN_PAD) return;
    int row = idx / IN_PAD;
    int col = idx - row * IN_PAD;
    dst[idx] = (col < IN_DIM) ? f2bf(src[(size_t)row * IN_DIM + col]) : 0;
}

__global__ __launch_bounds__(256) void k_cvt_w1t(const float* __restrict__ W1,
                                                 unsigned short* __restrict__ dst) {
    int idx = blockIdx.x * blockDim.x + threadIdx.x;
    if (idx >= HID_PAD * IN_PAD) return;
    int n = idx / IN_PAD;
    int k = idx - n * IN_PAD;
    dst[idx] = (k < IN_DIM && n < HID) ? f2bf(W1[(size_t)k * HID + n]) : 0;
}

// ---------------- GEMM1: bf16 128x128 tile (m97 2-barrier structure) ----------------

__global__ void k_gemm_bf(const unsigned short* __restrict__ A,
                          const unsigned short* __restrict__ Bt,
                          unsigned short* __restrict__ Cout,
                          int M, int N, int K) {
    __shared__ unsigned short ldsA[128 * 32];
    __shared__ unsigned short ldsB[128 * 32];

    const int tid = threadIdx.x;
    const int nbn = N >> 7;
    const int bm = blockIdx.x / nbn;
    const int bn = blockIdx.x - bm * nbn;

    const int wid = tid >> 6, lane = tid & 63;
    const int wr = wid >> 1, wc = wid & 1;
    const int lr = lane & 15, lg = lane >> 4;

    f32x4 acc[4][4] = {};

    const int r0 = tid >> 2, s0 = tid & 3;
    const unsigned short* Ag0 = A + ((size_t)bm * 128 + r0) * K + s0 * 8;
    const unsigned short* Ag1 = A + ((size_t)bm * 128 + 64 + r0) * K + s0 * 8;
    const unsigned short* Bg0 = Bt + ((size_t)bn * 128 + r0) * K + s0 * 8;
    const unsigned short* Bg1 = Bt + ((size_t)bn * 128 + 64 + r0) * K + s0 * 8;
    unsigned short* lA0 = ldsA + (size_t)(wid * 64) * 8;
    unsigned short* lA1 = ldsA + (size_t)(256 + wid * 64) * 8;
    unsigned short* lB0 = ldsB + (size_t)(wid * 64) * 8;
    unsigned short* lB1 = ldsB + (size_t)(256 + wid * 64) * 8;

    for (int kt = 0; kt < K; kt += 32) {
        __builtin_amdgcn_global_load_lds(
            (const __attribute__((address_space(1))) void*)(Ag0 + kt),
            (__attribute__((address_space(3))) void*)lA0, 16, 0, 0);
        __builtin_amdgcn_global_load_lds(
            (const __attribute__((address_space(1))) void*)(Ag1 + kt),
            (__attribute__((address_space(3))) void*)lA1, 16, 0, 0);
        __builtin_amdgcn_global_load_lds(
            (const __attribute__((address_space(1))) void*)(Bg0 + kt),
            (__attribute__((address_space(3))) void*)lB0, 16, 0, 0);
        __builtin_amdgcn_global_load_lds(
            (const __attribute__((address_space(1))) void*)(Bg1 + kt),
            (__attribute__((address_space(3))) void*)lB1, 16, 0, 0);
        __syncthreads();

        bf16x8 af[4], bfr[4];
#pragma unroll
        for (int i = 0; i < 4; i++) {
            af[i]  = *(const bf16x8*)&ldsA[((wr * 64 + i * 16 + lr) * 32) + lg * 8];
            bfr[i] = *(const bf16x8*)&ldsB[((wc * 64 + i * 16 + lr) * 32) + lg * 8];
        }
#pragma unroll
        for (int i = 0; i < 4; i++)
#pragma unroll
            for (int j = 0; j < 4; j++)
                acc[i][j] = __builtin_amdgcn_mfma_f32_16x16x32_bf16(af[i], bfr[j], acc[i][j], 0, 0, 0);
        __syncthreads();
    }

    const int row0 = bm * 128 + wr * 64;
    const int col0 = bn * 128 + wc * 64;
#pragma unroll
    for (int mi = 0; mi < 4; mi++) {
#pragma unroll
        for (int ni = 0; ni < 4; ni++) {
            int col = col0 + ni * 16 + lr;
#pragma unroll
            for (int j = 0; j < 4; j++) {
                int row = row0 + mi * 16 + lg * 4 + j;
                Cout[(size_t)row * N + col] = f2bf(acc[mi][ni][j]);
            }
        }
    }
}

// ---------------- GEMM2: R17 skeleton + 32x32x16 MFMA ----------------
// 256x256 tile, 8 waves (2Mx4N, 128x64/wave), full dbuf, 1 barrier/iter, split-K=2.
// MFMA = v_mfma_f32_32x32x16_bf16: 32 instr/K-tile (vs 64 16x16) at the higher-
// throughput 32x32 shape -> ~50% fewer issue slots, ~20% less matrix-pipe time.
// Operand layout (analogy with verified 16x16x32 pattern): A row = lane&31,
// k = (lane>>5)*8; B col = lane&31, same k. C/D (m74/m101-verified):
// col = lane&31, row = (reg&3) + 8*(reg>>2) + 4*(lane>>5).
// Staging/swizzles/vmcnt identical to R17 (conflicts measured 0).

__global__ __launch_bounds__(512, 2) void k_gemm2(const float* __restrict__ A,
                                                  const unsigned short* __restrict__ Bt,
                                                  float* __restrict__ Cpart) {
    __shared__ unsigned short ldsA[2][256 * BK2];     // 2 x 32 KB bf16 A
    __shared__ unsigned short ldsB[2][256 * BK2];     // 2 x 32 KB bf16 B

    const int tid = threadIdx.x;
    const int wg = blockIdx.x;                   // 256 blocks = 32 bm x 4 bn x 2 ks
    const int swz = (wg & 7) * 32 + (wg >> 3);   // bijective; XCD x owns bm in [4x,4x+4)
    const int bm = swz >> 3;                     // 0..31
    const int rem = swz & 7;
    const int ks = rem >> 2;                     // 0..1
    const int bn = rem & 3;                      // 0..3
    const size_t k0 = (size_t)ks * KH;

    const int wid = tid >> 6, lane = tid & 63;
    const int wr = wid >> 2, wc = wid & 3;       // 2 x 4 wave grid, 128x64 per wave
    const int l31 = lane & 31;                   // row/col within 32x32 frag
    const int kg  = lane >> 5;                   // k-group (0..1), 8 bf16 each

    f32x16 acc[4][2] = {};                       // 4 row-frags x 2 col-frags (128 f32)

    const float* Abase = A + ((size_t)bm * 256) * NN + k0;
    const unsigned short* Bbase = Bt + ((size_t)bn * 256) * NN + k0;

    const int arow = lane >> 4;                  // staging: row within 4-row chunk
    const int as   = lane & 15;                  // staging: 16B col slot (fp32 x4)
    const int bslot = (lane & 7) ^ (lane >> 3);  // B staging source slot (row&7 = lane>>3)

    float4 arS[8];

#define G2_LOAD_A(KT)                                                                       \
  {                                                                                         \
    _Pragma("unroll")                                                                       \
    for (int q = 0; q < 8; q++) {                                                           \
      const int c = wid * 8 + q;                                                            \
      arS[q] = *(const float4*)(Abase + (size_t)(c * 4 + arow) * NN + (KT) + as * 4);       \
    }                                                                                       \
  }

#define G2_WRITE_A(BUF)                                                                     \
  {                                                                                         \
    _Pragma("unroll")                                                                       \
    for (int q = 0; q < 8; q++) {                                                           \
      const int c = wid * 8 + q;                                                            \
      const int r = c * 4 + arow;                                                           \
      const int rm = (q & 1) * 4 + arow;        /* r & 7 */                                 \
      uint2 pk;                                                                             \
      pk.x = cvt_pk_bf16(arS[q].x, arS[q].y);                                               \
      pk.y = cvt_pk_bf16(arS[q].z, arS[q].w);                                               \
      *(uint2*)&ldsA[BUF][r * 64 + (((as >> 1) ^ rm) << 3) + (as & 1) * 4] = pk;            \
    }                                                                                       \
  }

#define G2_STAGE_B(BUF, KT)                                                                 \
  {                                                                                         \
    _Pragma("unroll")                                                                       \
    for (int q = 0; q < 4; q++) {                                                           \
      const int c = wid * 4 + q;                                                            \
      const int r = c * 8 + (lane >> 3);                                                    \
      __builtin_amdgcn_global_load_lds(                                                     \
          (const __attribute__((address_space(1))) void*)                                   \
              (Bbase + (size_t)r * NN + (KT) + bslot * 8),                                  \
          (__attribute__((address_space(3))) void*)(&ldsB[BUF][0] + c * 512),               \
          16, 0, 0);                                                                        \
    }                                                                                       \
  }

    // ---- prologue: A(0)->regs (oldest), B(0) DMA, cvt+write A(0) (B(0) flies)
    G2_LOAD_A(0);
    G2_STAGE_B(0, 0);
    G2_WRITE_A(0);
    asm volatile("s_waitcnt lgkmcnt(0)" ::: "memory");
    __builtin_amdgcn_sched_barrier(0);

    // ---- main loop: 64 tiles, ONE barrier per iteration
    for (int t = 0; t < NT2; ++t) {
        const int kt = t * BK2;
        const int cur = t & 1, nxt = cur ^ 1;

        // ph1: issue A(t+1) (newest), retire B(t) (oldest) with counted vmcnt
        if (t + 1 < NT2) {
            G2_LOAD_A(kt + BK2);
            asm volatile("s_waitcnt vmcnt(8)" ::: "memory");   // B(t) landed; A(t+1) flies
        } else {
            asm volatile("s_waitcnt vmcnt(0)" ::: "memory");
        }
        __builtin_amdgcn_sched_barrier(0);
        __builtin_amdgcn_s_barrier();        // everyone: B(t)/A(t) staged; nxt free to write
        __builtin_amdgcn_sched_barrier(0);

        // ph2: issue B(t+1) DMA into nxt — full-iteration flight
        if (t + 1 < NT2) G2_STAGE_B(nxt, kt + BK2);

        // ph3: compute tile t from cur — 4 kk slices (K=16 each), 8 MFMA/slice
#pragma unroll
        for (int kk = 0; kk < 4; kk++) {
            const int g = kk * 2 + kg;           // 8-bf16 k-slot index (0..7)
            bf16x8 af[4], bfr[2];
#pragma unroll
            for (int rb = 0; rb < 4; rb++) {
                const int r = wr * 128 + rb * 32 + l31;
                const int p = g ^ (r & 7);
                af[rb] = *(const bf16x8*)&ldsA[cur][r * 64 + p * 8];
            }
#pragma unroll
            for (int cb = 0; cb < 2; cb++) {
                const int r = wc * 64 + cb * 32 + l31;
                const int p = g ^ (r & 7);
                bfr[cb] = *(const bf16x8*)&ldsB[cur][r * 64 + p * 8];
            }
            __builtin_amdgcn_s_setprio(1);
#pragma unroll
            for (int rb = 0; rb < 4; rb++)
#pragma unroll
                for (int cb = 0; cb < 2; cb++)
                    acc[rb][cb] = __builtin_amdgcn_mfma_f32_32x32x16_bf16(af[rb], bfr[cb], acc[rb][cb], 0, 0, 0);
            __builtin_amdgcn_s_setprio(0);
        }

        // ph4: cvt+write A(t+1) into nxt (reg-dep counted wait; compute covered the load)
        if (t + 1 < NT2) {
            G2_WRITE_A(nxt);
        }
        asm volatile("s_waitcnt lgkmcnt(0)" ::: "memory");   // my ds_writes done before next barrier
        __builtin_amdgcn_sched_barrier(0);
    }

    // ---- epilogue: raw partial store (32x32 C layout: col=lane&31,
    //      row = (reg&3) + 8*(reg>>2) + 4*(lane>>5))
    float* Cout = Cpart + (size_t)ks * NN * HID_PAD;
    const int row0 = bm * 256 + wr * 128;
    const int col0 = bn * 256 + wc * 64;
#pragma unroll
    for (int rb = 0; rb < 4; rb++) {
#pragma unroll
        for (int cb = 0; cb < 2; cb++) {
            const int col = col0 + cb * 32 + l31;
#pragma unroll
            for (int reg = 0; reg < 16; reg++) {
                const int row = row0 + rb * 32 + (reg & 3) + 8 * (reg >> 2) + 4 * kg;
                Cout[(size_t)row * HID_PAD + col] = acc[rb][cb][reg];
            }
        }
    }
}

// ---------------- LayerNorm + head; fuses split-K reduce + bias + relu ----------------
__global__ __launch_bounds__(256) void k_ln_head(const float* __restrict__ p0,
                                                 const float* __restrict__ p1,
                                                 const float* __restrict__ b1,
                                                 const float* __restrict__ gamma,
                                                 const float* __restrict__ beta,
                                                 const float* __restrict__ Wm,
                                                 const float* __restrict__ bm,
                                                 float* __restrict__ out) {
    const int row = blockIdx.x;
    const int t = threadIdx.x;
    const float* h0 = p0 + (size_t)row * HID_PAD;
    const float* h1 = p1 + (size_t)row * HID_PAD;

    float v[4];
    float s = 0.f, ss = 0.f;
#pragma unroll
    for (int i = 0; i < 4; i++) {
        int ix = t + i * 256;
        float x = 0.f;
        if (ix < HID) {
            x = h0[ix] + h1[ix] + b1[ix];
            x = x > 0.f ? x : 0.f;
        }
        v[i] = x; s += x; ss += x * x;
    }
#pragma unroll
    for (int o = 32; o > 0; o >>= 1) { s += __shfl_down(s, o); ss += __shfl_down(ss, o); }

    __shared__ float rs[8], rss[8];
    const int wid = t >> 6, lane = t & 63;
    if (lane == 0) { rs[wid] = s; rss[wid] = ss; }
    __syncthreads();
    if (t == 0) {
        float a = 0.f, b = 0.f;
        for (int w = 0; w < 4; w++) { a += rs[w]; b += rss[w]; }
        rs[4] = a; rss[4] = b;
    }
    __syncthreads();
    const float mean = rs[4] * (1.0f / HID);
    const float var = rss[4] * (1.0f / HID) - mean * mean;
    const float rstd = rsqrtf(var + EPS);

    float q0 = 0.f, q1 = 0.f, q2 = 0.f, q3 = 0.f;
#pragma unroll
    for (int i = 0; i < 4; i++) {
        int ix = t + i * 256;
        if (ix < HID) {
            float hn = (v[i] - mean) * rstd * gamma[ix] + beta[ix];
            const float* w = Wm + (size_t)ix * 4;
            q0 += hn * w[0]; q1 += hn * w[1]; q2 += hn * w[2]; q3 += hn * w[3];
        }
    }
#pragma unroll
    for (int o = 32; o > 0; o >>= 1) {
        q0 += __shfl_down(q0, o); q1 += __shfl_down(q1, o);
        q2 += __shfl_down(q2, o); q3 += __shfl_down(q3, o);
    }
    __shared__ float rp[4][4];
    if (lane == 0) { rp[wid][0] = q0; rp[wid][1] = q1; rp[wid][2] = q2; rp[wid][3] = q3; }
    __syncthreads();
    if (t < 4) {
        float a = rp[0][t] + rp[1][t] + rp[2][t] + rp[3][t] + bm[t];
        out[(size_t)row * 4 + t] = a;
    }
}

// ---------------- launcher ----------------
extern "C" void kernel_launch(void* const* d_in, const int* in_sizes, int n_in,
                              void* d_out, int out_size, void* d_ws, size_t ws_size,
                              hipStream_t stream) {
    const float* adj      = (const float*)d_in[0];
    const float* features = (const float*)d_in[1];
    const float* W1       = (const float*)d_in[2];
    const float* b1       = (const float*)d_in[3];
    const float* gamma    = (const float*)d_in[4];
    const float* beta     = (const float*)d_in[5];
    const float* Wm       = (const float*)d_in[6];
    const float* bm       = (const float*)d_in[7];
    float* out = (float*)d_out;

    uint8_t* ws = (uint8_t*)d_ws;
    unsigned short* feat_p = (unsigned short*)ws;                 //  5,767,168 B
    unsigned short* w1t    = (unsigned short*)(ws + 5767168);     //    720,896 B
    unsigned short* xwt    = (unsigned short*)(ws + 6488064);     // 16,777,216 B
    float*          part0  = (float*)(ws + 23265280);             // 33,554,432 B
    float*          part1  = (float*)(ws + 56819712);             // 33,554,432 B (contiguous)

    k_cvt_feat<<<(NN * IN_PAD + 255) / 256, 256, 0, stream>>>(features, feat_p);
    k_cvt_w1t<<<(HID_PAD * IN_PAD + 255) / 256, 256, 0, stream>>>(W1, w1t);

    // GEMM1: xwt[1024][8192] = w1t * feat_p^T  (bf16 out)
    k_gemm_bf<<<(HID_PAD / 128) * (NN / 128), 256, 0, stream>>>(
        w1t, feat_p, xwt, HID_PAD, NN, IN_PAD);

    // GEMM2: 256x256 tile, 8 waves, dbuf, 1 barrier/iter, 32x32x16 MFMA, split-K=2
    k_gemm2<<<256, 512, 0, stream>>>(adj, xwt, part0);   // ks=1 half lands in part1

    k_ln_head<<<NN, 256, 0, stream>>>(part0, part1, b1, gamma, beta, Wm, bm, out);
}

// Round 23
// 212.676 us; speedup vs baseline: 1.0762x; 1.0762x over previous
//
#include <hip/hip_runtime.h>
#include <hip/hip_bf16.h>
#include <stdint.h>

#define NN 8192
#define IN_DIM 343
#define IN_PAD 352
#define HID 1000
#define HID_PAD 1024
#define EPS 1e-5f
#define KH 4096           // split-K half length
#define BK2 64            // GEMM2 K-step
#define NT2 (KH / BK2)    // 64 K-tiles per block

typedef __attribute__((ext_vector_type(8))) short bf16x8;
typedef __attribute__((ext_vector_type(4))) float f32x4;

static __device__ __forceinline__ unsigned short f2bf(float f) {
    union { float f; unsigned int u; } v; v.f = f;
    unsigned int u = v.u;
    unsigned int r = (u + 0x7FFFu + ((u >> 16) & 1u)) >> 16;   // RNE
    return (unsigned short)r;
}

static __device__ __forceinline__ unsigned cvt_pk_bf16(float lo, float hi) {
    unsigned r;
    asm("v_cvt_pk_bf16_f32 %0, %1, %2" : "=v"(r) : "v"(lo), "v"(hi));
    return r;
}

// ---------------- conversion kernels ----------------

__global__ __launch_bounds__(256) void k_cvt_feat(const float* __restrict__ src,
                                                  unsigned short* __restrict__ dst) {
    int idx = blockIdx.x * blockDim.x + threadIdx.x;
    if (idx >= NN * IN_PAD) return;
    int row = idx / IN_PAD;
    int col = idx - row * IN_PAD;
    dst[idx] = (col < IN_DIM) ? f2bf(src[(size_t)row * IN_DIM + col]) : 0;
}

__global__ __launch_bounds__(256) void k_cvt_w1t(const float* __restrict__ W1,
                                                 unsigned short* __restrict__ dst) {
    int idx = blockIdx.x * blockDim.x + threadIdx.x;
    if (idx >= HID_PAD * IN_PAD) return;
    int n = idx / IN_PAD;
    int k = idx - n * IN_PAD;
    dst[idx] = (k < IN_DIM && n < HID) ? f2bf(W1[(size_t)k * HID + n]) : 0;
}

// ---------------- GEMM1: bf16 128x128 tile (m97 2-barrier structure) ----------------

__global__ void k_gemm_bf(const unsigned short* __restrict__ A,
                          const unsigned short* __restrict__ Bt,
                          unsigned short* __restrict__ Cout,
                          int M, int N, int K) {
    __shared__ unsigned short ldsA[128 * 32];
    __shared__ unsigned short ldsB[128 * 32];

    const int tid = threadIdx.x;
    const int nbn = N >> 7;
    const int bm = blockIdx.x / nbn;
    const int bn = blockIdx.x - bm * nbn;

    const int wid = tid >> 6, lane = tid & 63;
    const int wr = wid >> 1, wc = wid & 1;
    const int lr = lane & 15, lg = lane >> 4;

    f32x4 acc[4][4] = {};

    const int r0 = tid >> 2, s0 = tid & 3;
    const unsigned short* Ag0 = A + ((size_t)bm * 128 + r0) * K + s0 * 8;
    const unsigned short* Ag1 = A + ((size_t)bm * 128 + 64 + r0) * K + s0 * 8;
    const unsigned short* Bg0 = Bt + ((size_t)bn * 128 + r0) * K + s0 * 8;
    const unsigned short* Bg1 = Bt + ((size_t)bn * 128 + 64 + r0) * K + s0 * 8;
    unsigned short* lA0 = ldsA + (size_t)(wid * 64) * 8;
    unsigned short* lA1 = ldsA + (size_t)(256 + wid * 64) * 8;
    unsigned short* lB0 = ldsB + (size_t)(wid * 64) * 8;
    unsigned short* lB1 = ldsB + (size_t)(256 + wid * 64) * 8;

    for (int kt = 0; kt < K; kt += 32) {
        __builtin_amdgcn_global_load_lds(
            (const __attribute__((address_space(1))) void*)(Ag0 + kt),
            (__attribute__((address_space(3))) void*)lA0, 16, 0, 0);
        __builtin_amdgcn_global_load_lds(
            (const __attribute__((address_space(1))) void*)(Ag1 + kt),
            (__attribute__((address_space(3))) void*)lA1, 16, 0, 0);
        __builtin_amdgcn_global_load_lds(
            (const __attribute__((address_space(1))) void*)(Bg0 + kt),
            (__attribute__((address_space(3))) void*)lB0, 16, 0, 0);
        __builtin_amdgcn_global_load_lds(
            (const __attribute__((address_space(1))) void*)(Bg1 + kt),
            (__attribute__((address_space(3))) void*)lB1, 16, 0, 0);
        __syncthreads();

        bf16x8 af[4], bfr[4];
#pragma unroll
        for (int i = 0; i < 4; i++) {
            af[i]  = *(const bf16x8*)&ldsA[((wr * 64 + i * 16 + lr) * 32) + lg * 8];
            bfr[i] = *(const bf16x8*)&ldsB[((wc * 64 + i * 16 + lr) * 32) + lg * 8];
        }
#pragma unroll
        for (int i = 0; i < 4; i++)
#pragma unroll
            for (int j = 0; j < 4; j++)
                acc[i][j] = __builtin_amdgcn_mfma_f32_16x16x32_bf16(af[i], bfr[j], acc[i][j], 0, 0, 0);
        __syncthreads();
    }

    const int row0 = bm * 128 + wr * 64;
    const int col0 = bn * 128 + wc * 64;
#pragma unroll
    for (int mi = 0; mi < 4; mi++) {
#pragma unroll
        for (int ni = 0; ni < 4; ni++) {
            int col = col0 + ni * 16 + lr;
#pragma unroll
            for (int j = 0; j < 4; j++) {
                int row = row0 + mi * 16 + lg * 4 + j;
                Cout[(size_t)row * N + col] = f2bf(acc[mi][ni][j]);
            }
        }
    }
}

// ---------------- GEMM2: 256x256 tile, 8 waves, full dbuf, 1 barrier/iter, split-K=2 ----------------
// (R17/R21, session best: GEMM2 ~203 us = 675 TF = measured 2-phase-class ceiling;
//  16x16x32 MFMA = zero bank conflicts, vs 32x32x16's inherent 4-way (R22).)
// 512 threads = 8 waves (2M x 4N), per-wave 128x64.
// LDS 128 KB: A 2x32KB bf16 (reg-staged cvt from fp32) + B 2x32KB bf16 (gload_lds).
// Iter t (cur=t&1, nxt=cur^1):
//   [issue A(t+1)->regs(8)] -> vmcnt(8) retires B(t) -> s_barrier ->
//   [issue B(t+1) DMA -> ldsB[nxt]: flies a FULL iteration] ->
//   compute(cur): 2kk x {12 ds_read_b128 + 32 MFMA} ->
//   [cvt+ds_write A(t+1) -> ldsA[nxt]; reg-dep = counted vmcnt] -> lgkmcnt(0).
// Swizzle (verified, conflicts=0): 16B-slot ^ (row&7), staging source pre-permuted.
// XCD swizzle: XCD x owns bm in [4x,4x+4); B panels L2/L3-resident.

__global__ __launch_bounds__(512, 2) void k_gemm2(const float* __restrict__ A,
                                                  const unsigned short* __restrict__ Bt,
                                                  float* __restrict__ Cpart) {
    __shared__ unsigned short ldsA[2][256 * BK2];     // 2 x 32 KB bf16 A
    __shared__ unsigned short ldsB[2][256 * BK2];     // 2 x 32 KB bf16 B

    const int tid = threadIdx.x;
    const int wg = blockIdx.x;                   // 256 blocks = 32 bm x 4 bn x 2 ks
    const int swz = (wg & 7) * 32 + (wg >> 3);   // bijective; XCD x owns bm in [4x,4x+4)
    const int bm = swz >> 3;                     // 0..31
    const int rem = swz & 7;
    const int ks = rem >> 2;                     // 0..1
    const int bn = rem & 3;                      // 0..3
    const size_t k0 = (size_t)ks * KH;

    const int wid = tid >> 6, lane = tid & 63;
    const int wr = wid >> 2, wc = wid & 3;       // 2 x 4 wave grid
    const int lr = lane & 15, lg = lane >> 4;

    f32x4 acc[8][4] = {};                        // per-wave 128x64 output

    const float* Abase = A + ((size_t)bm * 256) * NN + k0;
    const unsigned short* Bbase = Bt + ((size_t)bn * 256) * NN + k0;

    const int arow = lane >> 4;                  // 0..3 row within 4-row chunk
    const int as   = lane & 15;                  // 16B col slot (fp32 x4)
    const int bslot = (lane & 7) ^ (lane >> 3);  // B staging source slot (row&7 = lane>>3)

    float4 arS[8];

#define G2_LOAD_A(KT)                                                                       \
  {                                                                                         \
    _Pragma("unroll")                                                                       \
    for (int q = 0; q < 8; q++) {                                                           \
      const int c = wid * 8 + q;                                                            \
      arS[q] = *(const float4*)(Abase + (size_t)(c * 4 + arow) * NN + (KT) + as * 4);       \
    }                                                                                       \
  }

#define G2_WRITE_A(BUF)                                                                     \
  {                                                                                         \
    _Pragma("unroll")                                                                       \
    for (int q = 0; q < 8; q++) {                                                           \
      const int c = wid * 8 + q;                                                            \
      const int r = c * 4 + arow;                                                           \
      const int rm = (q & 1) * 4 + arow;        /* r & 7 */                                 \
      uint2 pk;                                                                             \
      pk.x = cvt_pk_bf16(arS[q].x, arS[q].y);                                               \
      pk.y = cvt_pk_bf16(arS[q].z, arS[q].w);                                               \
      *(uint2*)&ldsA[BUF][r * 64 + (((as >> 1) ^ rm) << 3) + (as & 1) * 4] = pk;            \
    }                                                                                       \
  }

#define G2_STAGE_B(BUF, KT)                                                                 \
  {                                                                                         \
    _Pragma("unroll")                                                                       \
    for (int q = 0; q < 4; q++) {                                                           \
      const int c = wid * 4 + q;                                                            \
      const int r = c * 8 + (lane >> 3);                                                    \
      __builtin_amdgcn_global_load_lds(                                                     \
          (const __attribute__((address_space(1))) void*)                                   \
              (Bbase + (size_t)r * NN + (KT) + bslot * 8),                                  \
          (__attribute__((address_space(3))) void*)(&ldsB[BUF][0] + c * 512),               \
          16, 0, 0);                                                                        \
    }                                                                                       \
  }

    // ---- prologue: A(0)->regs (oldest), B(0) DMA, cvt+write A(0) (B(0) flies)
    G2_LOAD_A(0);
    G2_STAGE_B(0, 0);
    G2_WRITE_A(0);
    asm volatile("s_waitcnt lgkmcnt(0)" ::: "memory");
    __builtin_amdgcn_sched_barrier(0);

    // ---- main loop: 64 tiles, ONE barrier per iteration
    for (int t = 0; t < NT2; ++t) {
        const int kt = t * BK2;
        const int cur = t & 1, nxt = cur ^ 1;

        // ph1: issue A(t+1) (newest), retire B(t) (oldest) with counted vmcnt
        if (t + 1 < NT2) {
            G2_LOAD_A(kt + BK2);
            asm volatile("s_waitcnt vmcnt(8)" ::: "memory");   // B(t) landed; A(t+1) flies
        } else {
            asm volatile("s_waitcnt vmcnt(0)" ::: "memory");
        }
        __builtin_amdgcn_sched_barrier(0);
        __builtin_amdgcn_s_barrier();        // everyone: B(t)/A(t) staged; nxt free to write
        __builtin_amdgcn_sched_barrier(0);

        // ph2: issue B(t+1) DMA into nxt — full-iteration flight
        if (t + 1 < NT2) G2_STAGE_B(nxt, kt + BK2);

        // ph3: compute tile t from cur
#pragma unroll
        for (int kk = 0; kk < 2; kk++) {
            bf16x8 af[8], bfr[4];
#pragma unroll
            for (int i = 0; i < 8; i++) {
                const int r = wr * 128 + i * 16 + lr;
                const int p = (kk * 4 + lg) ^ (lr & 7);        // r&7 == lr&7
                af[i] = *(const bf16x8*)&ldsA[cur][r * 64 + p * 8];
            }
#pragma unroll
            for (int j = 0; j < 4; j++) {
                const int r = wc * 64 + j * 16 + lr;
                const int p = (kk * 4 + lg) ^ (lr & 7);
                bfr[j] = *(const bf16x8*)&ldsB[cur][r * 64 + p * 8];
            }
            __builtin_amdgcn_s_setprio(1);
#pragma unroll
            for (int i = 0; i < 8; i++)
#pragma unroll
                for (int j = 0; j < 4; j++)
                    acc[i][j] = __builtin_amdgcn_mfma_f32_16x16x32_bf16(af[i], bfr[j], acc[i][j], 0, 0, 0);
            __builtin_amdgcn_s_setprio(0);
        }

        // ph4: cvt+write A(t+1) into nxt (reg-dep counted wait; compute covered the load)
        if (t + 1 < NT2) {
            G2_WRITE_A(nxt);
        }
        asm volatile("s_waitcnt lgkmcnt(0)" ::: "memory");   // my ds_writes done before next barrier
        __builtin_amdgcn_sched_barrier(0);
    }

    // ---- epilogue: raw partial store ----
    float* Cout = Cpart + (size_t)ks * NN * HID_PAD;
    const int row0 = bm * 256 + wr * 128;
    const int col0 = bn * 256 + wc * 64;
#pragma unroll
    for (int mi = 0; mi < 8; mi++) {
#pragma unroll
        for (int ni = 0; ni < 4; ni++) {
            int col = col0 + ni * 16 + lr;
#pragma unroll
            for (int j = 0; j < 4; j++) {
                int row = row0 + mi * 16 + lg * 4 + j;
                Cout[(size_t)row * HID_PAD + col] = acc[mi][ni][j];
            }
        }
    }
}

// ---------------- LayerNorm + head; fuses split-K reduce + bias + relu ----------------
__global__ __launch_bounds__(256) void k_ln_head(const float* __restrict__ p0,
                                                 const float* __restrict__ p1,
                                                 const float* __restrict__ b1,
                                                 const float* __restrict__ gamma,
                                                 const float* __restrict__ beta,
                                                 const float* __restrict__ Wm,
                                                 const float* __restrict__ bm,
                                                 float* __restrict__ out) {
    const int row = blockIdx.x;
    const int t = threadIdx.x;
    const float* h0 = p0 + (size_t)row * HID_PAD;
    const float* h1 = p1 + (size_t)row * HID_PAD;

    float v[4];
    float s = 0.f, ss = 0.f;
#pragma unroll
    for (int i = 0; i < 4; i++) {
        int ix = t + i * 256;
        float x = 0.f;
        if (ix < HID) {
            x = h0[ix] + h1[ix] + b1[ix];
            x = x > 0.f ? x : 0.f;
        }
        v[i] = x; s += x; ss += x * x;
    }
#pragma unroll
    for (int o = 32; o > 0; o >>= 1) { s += __shfl_down(s, o); ss += __shfl_down(ss, o); }

    __shared__ float rs[8], rss[8];
    const int wid = t >> 6, lane = t & 63;
    if (lane == 0) { rs[wid] = s; rss[wid] = ss; }
    __syncthreads();
    if (t == 0) {
        float a = 0.f, b = 0.f;
        for (int w = 0; w < 4; w++) { a += rs[w]; b += rss[w]; }
        rs[4] = a; rss[4] = b;
    }
    __syncthreads();
    const float mean = rs[4] * (1.0f / HID);
    const float var = rss[4] * (1.0f / HID) - mean * mean;
    const float rstd = rsqrtf(var + EPS);

    float q0 = 0.f, q1 = 0.f, q2 = 0.f, q3 = 0.f;
#pragma unroll
    for (int i = 0; i < 4; i++) {
        int ix = t + i * 256;
        if (ix < HID) {
            float hn = (v[i] - mean) * rstd * gamma[ix] + beta[ix];
            const float* w = Wm + (size_t)ix * 4;
            q0 += hn * w[0]; q1 += hn * w[1]; q2 += hn * w[2]; q3 += hn * w[3];
        }
    }
#pragma unroll
    for (int o = 32; o > 0; o >>= 1) {
        q0 += __shfl_down(q0, o); q1 += __shfl_down(q1, o);
        q2 += __shfl_down(q2, o); q3 += __shfl_down(q3, o);
    }
    __shared__ float rp[4][4];
    if (lane == 0) { rp[wid][0] = q0; rp[wid][1] = q1; rp[wid][2] = q2; rp[wid][3] = q3; }
    __syncthreads();
    if (t < 4) {
        float a = rp[0][t] + rp[1][t] + rp[2][t] + rp[3][t] + bm[t];
        out[(size_t)row * 4 + t] = a;
    }
}

// ---------------- launcher ----------------
extern "C" void kernel_launch(void* const* d_in, const int* in_sizes, int n_in,
                              void* d_out, int out_size, void* d_ws, size_t ws_size,
                              hipStream_t stream) {
    const float* adj      = (const float*)d_in[0];
    const float* features = (const float*)d_in[1];
    const float* W1       = (const float*)d_in[2];
    const float* b1       = (const float*)d_in[3];
    const float* gamma    = (const float*)d_in[4];
    const float* beta     = (const float*)d_in[5];
    const float* Wm       = (const float*)d_in[6];
    const float* bm       = (const float*)d_in[7];
    float* out = (float*)d_out;

    uint8_t* ws = (uint8_t*)d_ws;
    unsigned short* feat_p = (unsigned short*)ws;                 //  5,767,168 B
    unsigned short* w1t    = (unsigned short*)(ws + 5767168);     //    720,896 B
    unsigned short* xwt    = (unsigned short*)(ws + 6488064);     // 16,777,216 B
    float*          part0  = (float*)(ws + 23265280);             // 33,554,432 B
    float*          part1  = (float*)(ws + 56819712);             // 33,554,432 B (contiguous)

    k_cvt_feat<<<(NN * IN_PAD + 255) / 256, 256, 0, stream>>>(features, feat_p);
    k_cvt_w1t<<<(HID_PAD * IN_PAD + 255) / 256, 256, 0, stream>>>(W1, w1t);

    // GEMM1: xwt[1024][8192] = w1t * feat_p^T  (bf16 out)
    k_gemm_bf<<<(HID_PAD / 128) * (NN / 128), 256, 0, stream>>>(
        w1t, feat_p, xwt, HID_PAD, NN, IN_PAD);

    // GEMM2: 256x256 tile, 8 waves, dbuf, 1 barrier/iter, split-K=2 (grid 256 = 1/CU)
    k_gemm2<<<256, 512, 0, stream>>>(adj, xwt, part0);   // ks=1 half lands in part1

    k_ln_head<<<NN, 256, 0, stream>>>(part0, part1, b1, gamma, beta, Wm, bm, out);
}